// Round 2
// baseline (322.810 us; speedup 1.0000x reference)
//
#include <hip/hip_runtime.h>

// D = H = W = 128, NUM_STEPS = 7 (MONAI DVF2DDF scaling-and-squaring)
#define DD 128
constexpr int NV = DD * DD * DD;          // 2,097,152 voxels
constexpr float INV_SCALE = 1.0f / 128.0f; // 2^-NUM_STEPS

__device__ __forceinline__ void unpack_zyx(int tid, int& z, int& y, int& x) {
    x = tid & (DD - 1);
    y = (tid >> 7) & (DD - 1);
    z = tid >> 14;
}

__device__ __forceinline__ float clampd(float v) {
    return fminf(fmaxf(v, 0.0f), (float)(DD - 1));
}

// ---------------------------------------------------------------------------
// corner coords + weights (weight products in the exact verified order)
// ---------------------------------------------------------------------------
struct CornerW {
    int x0, x1, y0, y1, z0, z1;
    float w000, w001, w010, w011, w100, w101, w110, w111;
};

__device__ __forceinline__ CornerW make_cornerw(float cz, float cy, float cx) {
    CornerW c;
    float z0f = floorf(cz), y0f = floorf(cy), x0f = floorf(cx);
    float wz = cz - z0f, wy = cy - y0f, wx = cx - x0f;
    c.z0 = (int)z0f; c.y0 = (int)y0f; c.x0 = (int)x0f;
    c.z1 = min(c.z0 + 1, DD - 1);
    c.y1 = min(c.y0 + 1, DD - 1);
    c.x1 = min(c.x0 + 1, DD - 1);
    float omz = 1.0f - wz, omy = 1.0f - wy, omx = 1.0f - wx;
    c.w000 = omz * omy * omx; c.w001 = omz * omy * wx;
    c.w010 = omz * wy * omx;  c.w011 = omz * wy * wx;
    c.w100 = wz * omy * omx;  c.w101 = wz * omy * wx;
    c.w110 = wz * wy * omx;   c.w111 = wz * wy * wx;
    return c;
}

// ===========================================================================
// MAIN PATH: 12B-interleaved ping-pong in workspace, LDS-tiled step kernels
// ===========================================================================

// ---------------------------------------------------------------------------
// init (fused dvf pass-through): planar dvf -> interleaved A (scaled 2^-7),
// plus copy dvf to its output slot so final never touches dvf again.
// ---------------------------------------------------------------------------
__global__ __launch_bounds__(256)
void init_fused_kernel(const float* __restrict__ dvf,
                       float* __restrict__ A,
                       float* __restrict__ dvf_out) {
    int tid = blockIdx.x * blockDim.x + threadIdx.x;
    float v0 = dvf[tid];
    float v1 = dvf[tid + NV];
    float v2 = dvf[tid + 2 * NV];
    dvf_out[tid]          = v0;
    dvf_out[tid + NV]     = v1;
    dvf_out[tid + 2 * NV] = v2;
    float* p = A + 3 * tid;
    p[0] = v0 * INV_SCALE;
    p[1] = v1 * INV_SCALE;
    p[2] = v2 * INV_SCALE;
}

// ---------------------------------------------------------------------------
// LDS-tiled squaring step: dst = src + warp(src, src)
// Block tile: 16x8x8 voxels. Staged region: (16+6)x(8+6)x(8+6) = 22x14x14
// cells (halo 3 each side; clamped at volume borders), 12 B/cell = 50.5 KB.
// Corners falling inside the staged region (virtually always for this data,
// |d| <= ~1.4) read from LDS; otherwise per-voxel global-gather fallback.
// ---------------------------------------------------------------------------
#define TX 16
#define TY 8
#define TZ 8
#define HALO 3
#define RX (TX + 6)   // 22
#define RY (TY + 6)   // 14
#define RZ (TZ + 6)   // 14
constexpr int NCELLS = RX * RY * RZ;  // 4312

template <bool PLANAR_OUT>
__global__ __launch_bounds__(256)
void tile_step_kernel(const float* __restrict__ src, float* __restrict__ dst) {
    __shared__ float sf[NCELLS * 3];  // 51,744 B

    int bid = blockIdx.x;
    int bx = (bid & 7) * TX;          // 128/16 = 8 x-tiles
    int by = ((bid >> 3) & 15) * TY;  // 128/8  = 16 y-tiles
    int bz = (bid >> 7) * TZ;         // 128/8  = 16 z-tiles
    int t = threadIdx.x;

    // ---- stage region (coalesced-ish, clamped at borders) ----
    for (int c = t; c < NCELLS; c += 256) {
        int cx = c % RX;
        int rem = c / RX;
        int cy = rem % RY;
        int cz = rem / RY;
        int gx = min(max(bx - HALO + cx, 0), DD - 1);
        int gy = min(max(by - HALO + cy, 0), DD - 1);
        int gz = min(max(bz - HALO + cz, 0), DD - 1);
        const float* p = src + 3 * ((gz << 14) + (gy << 7) + gx);
        float a = p[0], b = p[1], d = p[2];
        sf[3 * c]     = a;
        sf[3 * c + 1] = b;
        sf[3 * c + 2] = d;
    }
    __syncthreads();

    // ---- compute 4 voxels per thread ----
    #pragma unroll
    for (int k = 0; k < 4; ++k) {
        int v = t + k * 256;
        int vx = v & (TX - 1);
        int vy = (v >> 4) & (TY - 1);
        int vz = v >> 7;
        int x = bx + vx, y = by + vy, z = bz + vz;

        int ocell = ((vz + HALO) * RY + (vy + HALO)) * RX + (vx + HALO);
        float d0 = sf[3 * ocell];
        float d1 = sf[3 * ocell + 1];
        float d2 = sf[3 * ocell + 2];

        float cz_ = clampd((float)z + d0);
        float cy_ = clampd((float)y + d1);
        float cx_ = clampd((float)x + d2);

        CornerW c = make_cornerw(cz_, cy_, cx_);

        int lx0 = c.x0 - bx + HALO, lx1 = c.x1 - bx + HALO;
        int ly0 = c.y0 - by + HALO, ly1 = c.y1 - by + HALO;
        int lz0 = c.z0 - bz + HALO, lz1 = c.z1 - bz + HALO;

        float r0, r1, r2;
        bool inl = (lx0 >= 0) & (lx1 <= RX - 1) &
                   (ly0 >= 0) & (ly1 <= RY - 1) &
                   (lz0 >= 0) & (lz1 <= RZ - 1);
        if (inl) {
            int r00 = (lz0 * RY + ly0) * RX;
            int r01 = (lz0 * RY + ly1) * RX;
            int r10 = (lz1 * RY + ly0) * RX;
            int r11 = (lz1 * RY + ly1) * RX;
            const float* p000 = sf + 3 * (r00 + lx0);
            const float* p001 = sf + 3 * (r00 + lx1);
            const float* p010 = sf + 3 * (r01 + lx0);
            const float* p011 = sf + 3 * (r01 + lx1);
            const float* p100 = sf + 3 * (r10 + lx0);
            const float* p101 = sf + 3 * (r10 + lx1);
            const float* p110 = sf + 3 * (r11 + lx0);
            const float* p111 = sf + 3 * (r11 + lx1);
            r0 = c.w000 * p000[0] + c.w001 * p001[0] + c.w010 * p010[0] + c.w011 * p011[0]
               + c.w100 * p100[0] + c.w101 * p101[0] + c.w110 * p110[0] + c.w111 * p111[0];
            r1 = c.w000 * p000[1] + c.w001 * p001[1] + c.w010 * p010[1] + c.w011 * p011[1]
               + c.w100 * p100[1] + c.w101 * p101[1] + c.w110 * p110[1] + c.w111 * p111[1];
            r2 = c.w000 * p000[2] + c.w001 * p001[2] + c.w010 * p010[2] + c.w011 * p011[2]
               + c.w100 * p100[2] + c.w101 * p101[2] + c.w110 * p110[2] + c.w111 * p111[2];
        } else {
            int zs0 = c.z0 << 14, zs1 = c.z1 << 14;
            int ys0 = c.y0 << 7,  ys1 = c.y1 << 7;
            const float* p000 = src + 3 * (zs0 + ys0 + c.x0);
            const float* p001 = src + 3 * (zs0 + ys0 + c.x1);
            const float* p010 = src + 3 * (zs0 + ys1 + c.x0);
            const float* p011 = src + 3 * (zs0 + ys1 + c.x1);
            const float* p100 = src + 3 * (zs1 + ys0 + c.x0);
            const float* p101 = src + 3 * (zs1 + ys0 + c.x1);
            const float* p110 = src + 3 * (zs1 + ys1 + c.x0);
            const float* p111 = src + 3 * (zs1 + ys1 + c.x1);
            r0 = c.w000 * p000[0] + c.w001 * p001[0] + c.w010 * p010[0] + c.w011 * p011[0]
               + c.w100 * p100[0] + c.w101 * p101[0] + c.w110 * p110[0] + c.w111 * p111[0];
            r1 = c.w000 * p000[1] + c.w001 * p001[1] + c.w010 * p010[1] + c.w011 * p011[1]
               + c.w100 * p100[1] + c.w101 * p101[1] + c.w110 * p110[1] + c.w111 * p111[1];
            r2 = c.w000 * p000[2] + c.w001 * p001[2] + c.w010 * p010[2] + c.w011 * p011[2]
               + c.w100 * p100[2] + c.w101 * p101[2] + c.w110 * p110[2] + c.w111 * p111[2];
        }

        r0 += d0; r1 += d1; r2 += d2;

        int gid = (z << 14) + (y << 7) + x;
        if (PLANAR_OUT) {
            dst[gid]          = r0;
            dst[gid + NV]     = r1;
            dst[gid + 2 * NV] = r2;
        } else {
            float* p = dst + 3 * gid;
            p[0] = r0; p[1] = r1; p[2] = r2;
        }
    }
}

// ---------------------------------------------------------------------------
// final: read planar ddf; bilinear-warp moving_image, nearest-warp label.
// (dvf pass-through already done in init_fused_kernel)
// ---------------------------------------------------------------------------
__global__ __launch_bounds__(256)
void final_kernel(const float* __restrict__ ddf,
                  const float* __restrict__ mimg,
                  const float* __restrict__ mlab,
                  float* __restrict__ pred_img,
                  float* __restrict__ pred_lab) {
    int tid = blockIdx.x * blockDim.x + threadIdx.x;
    int z, y, x;
    unpack_zyx(tid, z, y, x);

    float d0 = ddf[tid];
    float d1 = ddf[tid + NV];
    float d2 = ddf[tid + 2 * NV];

    float cz = clampd((float)z + d0);
    float cy = clampd((float)y + d1);
    float cx = clampd((float)x + d2);

    CornerW c = make_cornerw(cz, cy, cx);
    int zs0 = c.z0 << 14, zs1 = c.z1 << 14;
    int ys0 = c.y0 << 7,  ys1 = c.y1 << 7;

    float v = c.w000 * mimg[zs0 + ys0 + c.x0]
            + c.w001 * mimg[zs0 + ys0 + c.x1]
            + c.w010 * mimg[zs0 + ys1 + c.x0]
            + c.w011 * mimg[zs0 + ys1 + c.x1]
            + c.w100 * mimg[zs1 + ys0 + c.x0]
            + c.w101 * mimg[zs1 + ys0 + c.x1]
            + c.w110 * mimg[zs1 + ys1 + c.x0]
            + c.w111 * mimg[zs1 + ys1 + c.x1];
    pred_img[tid] = v;

    int zi = (int)rintf(cz);
    int yi = (int)rintf(cy);
    int xi = (int)rintf(cx);
    pred_lab[tid] = mlab[(zi << 14) + (yi << 7) + xi];
}

// ===========================================================================
// FALLBACK PATH (workspace too small): round-0 verified 261 µs pipeline
// ===========================================================================

__device__ __forceinline__ void trilerp3(const float* __restrict__ src,
                                         float cz, float cy, float cx,
                                         float& r0, float& r1, float& r2) {
    CornerW c = make_cornerw(cz, cy, cx);
    int zs0 = c.z0 << 14, zs1 = c.z1 << 14;
    int ys0 = c.y0 << 7,  ys1 = c.y1 << 7;
    const float* p000 = src + 3 * (zs0 + ys0 + c.x0);
    const float* p001 = src + 3 * (zs0 + ys0 + c.x1);
    const float* p010 = src + 3 * (zs0 + ys1 + c.x0);
    const float* p011 = src + 3 * (zs0 + ys1 + c.x1);
    const float* p100 = src + 3 * (zs1 + ys0 + c.x0);
    const float* p101 = src + 3 * (zs1 + ys0 + c.x1);
    const float* p110 = src + 3 * (zs1 + ys1 + c.x0);
    const float* p111 = src + 3 * (zs1 + ys1 + c.x1);
    r0 = c.w000 * p000[0] + c.w001 * p001[0] + c.w010 * p010[0] + c.w011 * p011[0]
       + c.w100 * p100[0] + c.w101 * p101[0] + c.w110 * p110[0] + c.w111 * p111[0];
    r1 = c.w000 * p000[1] + c.w001 * p001[1] + c.w010 * p010[1] + c.w011 * p011[1]
       + c.w100 * p100[1] + c.w101 * p101[1] + c.w110 * p110[1] + c.w111 * p111[1];
    r2 = c.w000 * p000[2] + c.w001 * p001[2] + c.w010 * p010[2] + c.w011 * p011[2]
       + c.w100 * p100[2] + c.w101 * p101[2] + c.w110 * p110[2] + c.w111 * p111[2];
}

__global__ __launch_bounds__(256)
void init_kernel(const float* __restrict__ dvf, float* __restrict__ A) {
    int tid = blockIdx.x * blockDim.x + threadIdx.x;
    float d0 = dvf[tid] * INV_SCALE;
    float d1 = dvf[tid + NV] * INV_SCALE;
    float d2 = dvf[tid + 2 * NV] * INV_SCALE;
    float* p = A + 3 * tid;
    p[0] = d0; p[1] = d1; p[2] = d2;
}

template <bool PLANAR_OUT>
__global__ __launch_bounds__(256)
void step_kernel(const float* __restrict__ src, float* __restrict__ dst) {
    int tid = blockIdx.x * blockDim.x + threadIdx.x;
    int z, y, x;
    unpack_zyx(tid, z, y, x);
    const float* s = src + 3 * tid;
    float d0 = s[0], d1 = s[1], d2 = s[2];
    float cz = clampd((float)z + d0);
    float cy = clampd((float)y + d1);
    float cx = clampd((float)x + d2);
    float r0, r1, r2;
    trilerp3(src, cz, cy, cx, r0, r1, r2);
    r0 += d0; r1 += d1; r2 += d2;
    if (PLANAR_OUT) {
        dst[tid]          = r0;
        dst[tid + NV]     = r1;
        dst[tid + 2 * NV] = r2;
    } else {
        float* p = dst + 3 * tid;
        p[0] = r0; p[1] = r1; p[2] = r2;
    }
}

__global__ __launch_bounds__(256)
void final_kernel_fb(const float* __restrict__ ddf,
                     const float* __restrict__ mimg,
                     const float* __restrict__ mlab,
                     const float* __restrict__ dvf,
                     float* __restrict__ pred_img,
                     float* __restrict__ pred_lab,
                     float* __restrict__ dvf_out) {
    int tid = blockIdx.x * blockDim.x + threadIdx.x;
    int z, y, x;
    unpack_zyx(tid, z, y, x);
    float d0 = ddf[tid];
    float d1 = ddf[tid + NV];
    float d2 = ddf[tid + 2 * NV];
    float cz = clampd((float)z + d0);
    float cy = clampd((float)y + d1);
    float cx = clampd((float)x + d2);
    CornerW c = make_cornerw(cz, cy, cx);
    int zs0 = c.z0 << 14, zs1 = c.z1 << 14;
    int ys0 = c.y0 << 7,  ys1 = c.y1 << 7;
    float v = c.w000 * mimg[zs0 + ys0 + c.x0]
            + c.w001 * mimg[zs0 + ys0 + c.x1]
            + c.w010 * mimg[zs0 + ys1 + c.x0]
            + c.w011 * mimg[zs0 + ys1 + c.x1]
            + c.w100 * mimg[zs1 + ys0 + c.x0]
            + c.w101 * mimg[zs1 + ys0 + c.x1]
            + c.w110 * mimg[zs1 + ys1 + c.x0]
            + c.w111 * mimg[zs1 + ys1 + c.x1];
    pred_img[tid] = v;
    int zi = (int)rintf(cz);
    int yi = (int)rintf(cy);
    int xi = (int)rintf(cx);
    pred_lab[tid] = mlab[(zi << 14) + (yi << 7) + xi];
    dvf_out[tid]          = dvf[tid];
    dvf_out[tid + NV]     = dvf[tid + NV];
    dvf_out[tid + 2 * NV] = dvf[tid + 2 * NV];
}

// ===========================================================================

extern "C" void kernel_launch(void* const* d_in, const int* in_sizes, int n_in,
                              void* d_out, int out_size, void* d_ws, size_t ws_size,
                              hipStream_t stream) {
    const float* dvf  = (const float*)d_in[0];
    const float* mimg = (const float*)d_in[1];
    // d_in[2] = fixed_image: unused by the reference outputs
    const float* mlab = (const float*)d_in[3];

    float* out      = (float*)d_out;
    float* ddf_out  = out;              // slot 0: ddf  [3,D,H,W]
    float* pred_img = out + 3 * NV;     // slot 1
    float* pred_lab = out + 4 * NV;     // slot 2
    float* dvf_out  = out + 5 * NV;     // slot 3: dvf pass-through

    dim3 block(256);
    dim3 grid(NV / 256);       // 8192 blocks (init / final)
    dim3 tgrid(NV / 1024);     // 2048 tile blocks (16x8x8 voxels each)

    size_t need = (size_t)2 * NV * 3 * sizeof(float);  // 48 MiB ping-pong
    if (d_ws != nullptr && ws_size >= need) {
        float* A = (float*)d_ws;          // interleaved 12B
        float* B = A + (size_t)3 * NV;
        init_fused_kernel<<<grid, block, 0, stream>>>(dvf, A, dvf_out);
        tile_step_kernel<false><<<tgrid, block, 0, stream>>>(A, B);  // 1
        tile_step_kernel<false><<<tgrid, block, 0, stream>>>(B, A);  // 2
        tile_step_kernel<false><<<tgrid, block, 0, stream>>>(A, B);  // 3
        tile_step_kernel<false><<<tgrid, block, 0, stream>>>(B, A);  // 4
        tile_step_kernel<false><<<tgrid, block, 0, stream>>>(A, B);  // 5
        tile_step_kernel<false><<<tgrid, block, 0, stream>>>(B, A);  // 6
        tile_step_kernel<true ><<<tgrid, block, 0, stream>>>(A, ddf_out); // 7
        final_kernel<<<grid, block, 0, stream>>>(ddf_out, mimg, mlab,
                                                 pred_img, pred_lab);
    } else {
        // fallback: round-0 verified pipeline (scratch inside d_out)
        float* A = dvf_out;
        float* B = ddf_out;
        init_kernel<<<grid, block, 0, stream>>>(dvf, A);
        step_kernel<false><<<grid, block, 0, stream>>>(A, B);  // 1
        step_kernel<false><<<grid, block, 0, stream>>>(B, A);  // 2
        step_kernel<false><<<grid, block, 0, stream>>>(A, B);  // 3
        step_kernel<false><<<grid, block, 0, stream>>>(B, A);  // 4
        step_kernel<false><<<grid, block, 0, stream>>>(A, B);  // 5
        step_kernel<false><<<grid, block, 0, stream>>>(B, A);  // 6
        step_kernel<true ><<<grid, block, 0, stream>>>(A, B);  // 7
        final_kernel_fb<<<grid, block, 0, stream>>>(B, mimg, mlab, dvf,
                                                    pred_img, pred_lab, dvf_out);
    }
}

// Round 4
// 259.364 us; speedup vs baseline: 1.2446x; 1.2446x over previous
//
#include <hip/hip_runtime.h>

// D = H = W = 128, NUM_STEPS = 7 (MONAI DVF2DDF scaling-and-squaring)
#define DD 128
constexpr int NV = DD * DD * DD;          // 2,097,152 voxels
constexpr float INV_SCALE = 1.0f / 128.0f; // 2^-NUM_STEPS
#define NXCD 8

// XCD-consistent block swizzle: dispatch round-robins blocks across the 8
// XCDs (xcd = blockIdx % 8).  vbid = (b%8)*cpx + b/8 gives XCD i the
// CONTIGUOUS slab [i*cpx, (i+1)*cpx) of virtual block ids, so the same
// z-slab is produced and consumed on the same XCD's L2 in every dispatch.
__device__ __forceinline__ int swz(int b, int cpx) {
    return (b & (NXCD - 1)) * cpx + (b >> 3);
}

__device__ __forceinline__ void unpack_zyx(int tid, int& z, int& y, int& x) {
    x = tid & (DD - 1);
    y = (tid >> 7) & (DD - 1);
    z = tid >> 14;
}

__device__ __forceinline__ float clampd(float v) {
    return fminf(fmaxf(v, 0.0f), (float)(DD - 1));
}

// ---------------------------------------------------------------------------
// trilinear sample of interleaved 3-channel field (EXACT round-0 expression
// order — verified bit-stable, absmax 0.00390625)
// ---------------------------------------------------------------------------
__device__ __forceinline__ void trilerp3(const float* __restrict__ src,
                                         float cz, float cy, float cx,
                                         float& r0, float& r1, float& r2) {
    float z0f = floorf(cz), y0f = floorf(cy), x0f = floorf(cx);
    float wz = cz - z0f, wy = cy - y0f, wx = cx - x0f;
    int z0 = (int)z0f, y0 = (int)y0f, x0 = (int)x0f;
    int z1 = min(z0 + 1, DD - 1);
    int y1 = min(y0 + 1, DD - 1);
    int x1 = min(x0 + 1, DD - 1);
    float omz = 1.0f - wz, omy = 1.0f - wy, omx = 1.0f - wx;

    int zs0 = z0 << 14, zs1 = z1 << 14;
    int ys0 = y0 << 7,  ys1 = y1 << 7;

    const float* p000 = src + 3 * (zs0 + ys0 + x0);
    const float* p001 = src + 3 * (zs0 + ys0 + x1);
    const float* p010 = src + 3 * (zs0 + ys1 + x0);
    const float* p011 = src + 3 * (zs0 + ys1 + x1);
    const float* p100 = src + 3 * (zs1 + ys0 + x0);
    const float* p101 = src + 3 * (zs1 + ys0 + x1);
    const float* p110 = src + 3 * (zs1 + ys1 + x0);
    const float* p111 = src + 3 * (zs1 + ys1 + x1);

    float w000 = omz * omy * omx, w001 = omz * omy * wx;
    float w010 = omz * wy * omx,  w011 = omz * wy * wx;
    float w100 = wz * omy * omx,  w101 = wz * omy * wx;
    float w110 = wz * wy * omx,   w111 = wz * wy * wx;

    r0 = w000 * p000[0] + w001 * p001[0] + w010 * p010[0] + w011 * p011[0]
       + w100 * p100[0] + w101 * p101[0] + w110 * p110[0] + w111 * p111[0];
    r1 = w000 * p000[1] + w001 * p001[1] + w010 * p010[1] + w011 * p011[1]
       + w100 * p100[1] + w101 * p101[1] + w110 * p110[1] + w111 * p111[1];
    r2 = w000 * p000[2] + w001 * p001[2] + w010 * p010[2] + w011 * p011[2]
       + w100 * p100[2] + w101 * p101[2] + w110 * p110[2] + w111 * p111[2];
}

// ===========================================================================
// MAIN PATH: workspace ping-pong, XCD-swizzled, 8 dispatches
// ===========================================================================

// ---------------------------------------------------------------------------
// init: 4 voxels/thread, every access dwordx4.
// planar dvf -> interleaved A (scaled 2^-7) + dvf pass-through copy.
// grid = NV/1024 = 2048 blocks, cpx = 256
// ---------------------------------------------------------------------------
__global__ __launch_bounds__(256)
void init_fused_kernel(const float* __restrict__ dvf,
                       float* __restrict__ A,
                       float* __restrict__ dvf_out) {
    int vbid = swz(blockIdx.x, 2048 / NXCD);
    int base = vbid * 1024 + threadIdx.x * 4;   // 4 consecutive voxels

    float4 a = *(const float4*)(dvf + base);
    float4 b = *(const float4*)(dvf + base + NV);
    float4 c = *(const float4*)(dvf + base + 2 * NV);

    *(float4*)(dvf_out + base)          = a;
    *(float4*)(dvf_out + base + NV)     = b;
    *(float4*)(dvf_out + base + 2 * NV) = c;

    float4 o0 = make_float4(a.x * INV_SCALE, b.x * INV_SCALE, c.x * INV_SCALE,
                            a.y * INV_SCALE);
    float4 o1 = make_float4(b.y * INV_SCALE, c.y * INV_SCALE, a.z * INV_SCALE,
                            b.z * INV_SCALE);
    float4 o2 = make_float4(c.z * INV_SCALE, a.w * INV_SCALE, b.w * INV_SCALE,
                            c.w * INV_SCALE);
    float* p = A + 3 * base;
    *(float4*)(p)     = o0;
    *(float4*)(p + 4) = o1;
    *(float4*)(p + 8) = o2;
}

// ---------------------------------------------------------------------------
// squaring step (steps 1..6): dst = src + warp(src, src), interleaved 12B.
// Identical arithmetic/memory pattern to the verified round-0 kernel,
// plus XCD swizzle.  grid = 8192, cpx = 1024
// ---------------------------------------------------------------------------
__global__ __launch_bounds__(256)
void step_kernel(const float* __restrict__ src, float* __restrict__ dst) {
    int vbid = swz(blockIdx.x, 8192 / NXCD);
    int tid = vbid * 256 + threadIdx.x;
    int z, y, x;
    unpack_zyx(tid, z, y, x);

    const float* s = src + 3 * tid;
    float d0 = s[0], d1 = s[1], d2 = s[2];

    float cz = clampd((float)z + d0);
    float cy = clampd((float)y + d1);
    float cx = clampd((float)x + d2);

    float r0, r1, r2;
    trilerp3(src, cz, cy, cx, r0, r1, r2);

    r0 += d0; r1 += d1; r2 += d2;

    float* p = dst + 3 * tid;
    p[0] = r0; p[1] = r1; p[2] = r2;
}

// ---------------------------------------------------------------------------
// fused step 7 + final: computes ddf in registers, writes planar ddf, then
// immediately warps moving_image (bilinear) and moving_label (nearest) with
// the register ddf (bit-identical to store-then-reload).
// ---------------------------------------------------------------------------
__global__ __launch_bounds__(256)
void step7_final_kernel(const float* __restrict__ src,
                        const float* __restrict__ mimg,
                        const float* __restrict__ mlab,
                        float* __restrict__ ddf_out,
                        float* __restrict__ pred_img,
                        float* __restrict__ pred_lab) {
    int vbid = swz(blockIdx.x, 8192 / NXCD);
    int tid = vbid * 256 + threadIdx.x;
    int z, y, x;
    unpack_zyx(tid, z, y, x);

    const float* s = src + 3 * tid;
    float d0 = s[0], d1 = s[1], d2 = s[2];

    float cz = clampd((float)z + d0);
    float cy = clampd((float)y + d1);
    float cx = clampd((float)x + d2);

    float r0, r1, r2;
    trilerp3(src, cz, cy, cx, r0, r1, r2);
    r0 += d0; r1 += d1; r2 += d2;

    ddf_out[tid]          = r0;
    ddf_out[tid + NV]     = r1;
    ddf_out[tid + 2 * NV] = r2;

    // final warp with the just-computed ddf (same values final_kernel reloaded)
    float fz = clampd((float)z + r0);
    float fy = clampd((float)y + r1);
    float fx = clampd((float)x + r2);

    {
        float z0f = floorf(fz), y0f = floorf(fy), x0f = floorf(fx);
        float wz = fz - z0f, wy = fy - y0f, wx = fx - x0f;
        int z0 = (int)z0f, y0 = (int)y0f, x0 = (int)x0f;
        int z1 = min(z0 + 1, DD - 1);
        int y1 = min(y0 + 1, DD - 1);
        int x1 = min(x0 + 1, DD - 1);
        float omz = 1.0f - wz, omy = 1.0f - wy, omx = 1.0f - wx;
        int zs0 = z0 << 14, zs1 = z1 << 14;
        int ys0 = y0 << 7,  ys1 = y1 << 7;

        float v = omz * omy * omx * mimg[zs0 + ys0 + x0]
                + omz * omy * wx  * mimg[zs0 + ys0 + x1]
                + omz * wy * omx  * mimg[zs0 + ys1 + x0]
                + omz * wy * wx   * mimg[zs0 + ys1 + x1]
                + wz * omy * omx  * mimg[zs1 + ys0 + x0]
                + wz * omy * wx   * mimg[zs1 + ys0 + x1]
                + wz * wy * omx   * mimg[zs1 + ys1 + x0]
                + wz * wy * wx    * mimg[zs1 + ys1 + x1];
        pred_img[tid] = v;
    }

    {
        int zi = (int)rintf(fz);
        int yi = (int)rintf(fy);
        int xi = (int)rintf(fx);
        pred_lab[tid] = mlab[(zi << 14) + (yi << 7) + xi];
    }
}

// ===========================================================================
// FALLBACK PATH (workspace too small): round-0 verified 261 µs pipeline
// ===========================================================================

__global__ __launch_bounds__(256)
void init_kernel_fb(const float* __restrict__ dvf, float* __restrict__ A) {
    int tid = blockIdx.x * blockDim.x + threadIdx.x;
    float d0 = dvf[tid] * INV_SCALE;
    float d1 = dvf[tid + NV] * INV_SCALE;
    float d2 = dvf[tid + 2 * NV] * INV_SCALE;
    float* p = A + 3 * tid;
    p[0] = d0; p[1] = d1; p[2] = d2;
}

template <bool PLANAR_OUT>
__global__ __launch_bounds__(256)
void step_kernel_fb(const float* __restrict__ src, float* __restrict__ dst) {
    int tid = blockIdx.x * blockDim.x + threadIdx.x;
    int z, y, x;
    unpack_zyx(tid, z, y, x);
    const float* s = src + 3 * tid;
    float d0 = s[0], d1 = s[1], d2 = s[2];
    float cz = clampd((float)z + d0);
    float cy = clampd((float)y + d1);
    float cx = clampd((float)x + d2);
    float r0, r1, r2;
    trilerp3(src, cz, cy, cx, r0, r1, r2);
    r0 += d0; r1 += d1; r2 += d2;
    if (PLANAR_OUT) {
        dst[tid]          = r0;
        dst[tid + NV]     = r1;
        dst[tid + 2 * NV] = r2;
    } else {
        float* p = dst + 3 * tid;
        p[0] = r0; p[1] = r1; p[2] = r2;
    }
}

__global__ __launch_bounds__(256)
void final_kernel_fb(const float* __restrict__ ddf,
                     const float* __restrict__ mimg,
                     const float* __restrict__ mlab,
                     const float* __restrict__ dvf,
                     float* __restrict__ pred_img,
                     float* __restrict__ pred_lab,
                     float* __restrict__ dvf_out) {
    int tid = blockIdx.x * blockDim.x + threadIdx.x;
    int z, y, x;
    unpack_zyx(tid, z, y, x);
    float d0 = ddf[tid];
    float d1 = ddf[tid + NV];
    float d2 = ddf[tid + 2 * NV];
    float cz = clampd((float)z + d0);
    float cy = clampd((float)y + d1);
    float cx = clampd((float)x + d2);
    {
        float z0f = floorf(cz), y0f = floorf(cy), x0f = floorf(cx);
        float wz = cz - z0f, wy = cy - y0f, wx = cx - x0f;
        int z0 = (int)z0f, y0 = (int)y0f, x0 = (int)x0f;
        int z1 = min(z0 + 1, DD - 1);
        int y1 = min(y0 + 1, DD - 1);
        int x1 = min(x0 + 1, DD - 1);
        float omz = 1.0f - wz, omy = 1.0f - wy, omx = 1.0f - wx;
        int zs0 = z0 << 14, zs1 = z1 << 14;
        int ys0 = y0 << 7,  ys1 = y1 << 7;
        float v = omz * omy * omx * mimg[zs0 + ys0 + x0]
                + omz * omy * wx  * mimg[zs0 + ys0 + x1]
                + omz * wy * omx  * mimg[zs0 + ys1 + x0]
                + omz * wy * wx   * mimg[zs0 + ys1 + x1]
                + wz * omy * omx  * mimg[zs1 + ys0 + x0]
                + wz * omy * wx   * mimg[zs1 + ys0 + x1]
                + wz * wy * omx   * mimg[zs1 + ys1 + x0]
                + wz * wy * wx    * mimg[zs1 + ys1 + x1];
        pred_img[tid] = v;
    }
    int zi = (int)rintf(cz);
    int yi = (int)rintf(cy);
    int xi = (int)rintf(cx);
    pred_lab[tid] = mlab[(zi << 14) + (yi << 7) + xi];
    dvf_out[tid]          = dvf[tid];
    dvf_out[tid + NV]     = dvf[tid + NV];
    dvf_out[tid + 2 * NV] = dvf[tid + 2 * NV];
}

// ===========================================================================

extern "C" void kernel_launch(void* const* d_in, const int* in_sizes, int n_in,
                              void* d_out, int out_size, void* d_ws, size_t ws_size,
                              hipStream_t stream) {
    const float* dvf  = (const float*)d_in[0];
    const float* mimg = (const float*)d_in[1];
    // d_in[2] = fixed_image: unused by the reference outputs
    const float* mlab = (const float*)d_in[3];

    float* out      = (float*)d_out;
    float* ddf_out  = out;              // slot 0: ddf  [3,D,H,W]
    float* pred_img = out + 3 * NV;     // slot 1
    float* pred_lab = out + 4 * NV;     // slot 2
    float* dvf_out  = out + 5 * NV;     // slot 3: dvf pass-through

    dim3 block(256);
    dim3 grid(NV / 256);       // 8192 blocks (steps / fused final)
    dim3 igrid(NV / 1024);     // 2048 blocks (vectorized init)

    size_t need = (size_t)2 * NV * 3 * sizeof(float);  // 48 MiB ping-pong
    if (d_ws != nullptr && ws_size >= need) {
        float* A = (float*)d_ws;          // interleaved 12B
        float* B = A + (size_t)3 * NV;
        init_fused_kernel<<<igrid, block, 0, stream>>>(dvf, A, dvf_out);
        step_kernel<<<grid, block, 0, stream>>>(A, B);  // 1
        step_kernel<<<grid, block, 0, stream>>>(B, A);  // 2
        step_kernel<<<grid, block, 0, stream>>>(A, B);  // 3
        step_kernel<<<grid, block, 0, stream>>>(B, A);  // 4
        step_kernel<<<grid, block, 0, stream>>>(A, B);  // 5
        step_kernel<<<grid, block, 0, stream>>>(B, A);  // 6
        step7_final_kernel<<<grid, block, 0, stream>>>(A, mimg, mlab,
                                                       ddf_out, pred_img,
                                                       pred_lab);         // 7
    } else {
        // fallback: round-0 verified pipeline (scratch inside d_out)
        float* A = dvf_out;
        float* B = ddf_out;
        init_kernel_fb<<<grid, block, 0, stream>>>(dvf, A);
        step_kernel_fb<false><<<grid, block, 0, stream>>>(A, B);  // 1
        step_kernel_fb<false><<<grid, block, 0, stream>>>(B, A);  // 2
        step_kernel_fb<false><<<grid, block, 0, stream>>>(A, B);  // 3
        step_kernel_fb<false><<<grid, block, 0, stream>>>(B, A);  // 4
        step_kernel_fb<false><<<grid, block, 0, stream>>>(A, B);  // 5
        step_kernel_fb<false><<<grid, block, 0, stream>>>(B, A);  // 6
        step_kernel_fb<true ><<<grid, block, 0, stream>>>(A, B);  // 7
        final_kernel_fb<<<grid, block, 0, stream>>>(B, mimg, mlab, dvf,
                                                    pred_img, pred_lab, dvf_out);
    }
}

// Round 5
// 259.274 us; speedup vs baseline: 1.2451x; 1.0003x over previous
//
#include <hip/hip_runtime.h>

// D = H = W = 128, NUM_STEPS = 7 (MONAI DVF2DDF scaling-and-squaring)
#define DD 128
constexpr int NV = DD * DD * DD;          // 2,097,152 voxels
constexpr float INV_SCALE = 1.0f / 128.0f; // 2^-NUM_STEPS
#define NXCD 8

// consistent bijective block swizzle (neutral in r4, kept: harmless, and keeps
// producer/consumer block->XCD mapping stable across dispatches)
__device__ __forceinline__ int swz(int b, int cpx) {
    return (b & (NXCD - 1)) * cpx + (b >> 3);
}

__device__ __forceinline__ void unpack_zyx(int tid, int& z, int& y, int& x) {
    x = tid & (DD - 1);
    y = (tid >> 7) & (DD - 1);
    z = tid >> 14;
}

__device__ __forceinline__ float clampd(float v) {
    return fminf(fmaxf(v, 0.0f), (float)(DD - 1));
}

// ---------------------------------------------------------------------------
// trilinear sample of interleaved 3-channel field (EXACT round-0 expression
// order — verified bit-stable, absmax 0.00390625)
// ---------------------------------------------------------------------------
__device__ __forceinline__ void trilerp3(const float* __restrict__ src,
                                         float cz, float cy, float cx,
                                         float& r0, float& r1, float& r2) {
    float z0f = floorf(cz), y0f = floorf(cy), x0f = floorf(cx);
    float wz = cz - z0f, wy = cy - y0f, wx = cx - x0f;
    int z0 = (int)z0f, y0 = (int)y0f, x0 = (int)x0f;
    int z1 = min(z0 + 1, DD - 1);
    int y1 = min(y0 + 1, DD - 1);
    int x1 = min(x0 + 1, DD - 1);
    float omz = 1.0f - wz, omy = 1.0f - wy, omx = 1.0f - wx;

    int zs0 = z0 << 14, zs1 = z1 << 14;
    int ys0 = y0 << 7,  ys1 = y1 << 7;

    const float* p000 = src + 3 * (zs0 + ys0 + x0);
    const float* p001 = src + 3 * (zs0 + ys0 + x1);
    const float* p010 = src + 3 * (zs0 + ys1 + x0);
    const float* p011 = src + 3 * (zs0 + ys1 + x1);
    const float* p100 = src + 3 * (zs1 + ys0 + x0);
    const float* p101 = src + 3 * (zs1 + ys0 + x1);
    const float* p110 = src + 3 * (zs1 + ys1 + x0);
    const float* p111 = src + 3 * (zs1 + ys1 + x1);

    float w000 = omz * omy * omx, w001 = omz * omy * wx;
    float w010 = omz * wy * omx,  w011 = omz * wy * wx;
    float w100 = wz * omy * omx,  w101 = wz * omy * wx;
    float w110 = wz * wy * omx,   w111 = wz * wy * wx;

    r0 = w000 * p000[0] + w001 * p001[0] + w010 * p010[0] + w011 * p011[0]
       + w100 * p100[0] + w101 * p101[0] + w110 * p110[0] + w111 * p111[0];
    r1 = w000 * p000[1] + w001 * p001[1] + w010 * p010[1] + w011 * p011[1]
       + w100 * p100[1] + w101 * p101[1] + w110 * p110[1] + w111 * p111[1];
    r2 = w000 * p000[2] + w001 * p001[2] + w010 * p010[2] + w011 * p011[2]
       + w100 * p100[2] + w101 * p101[2] + w110 * p110[2] + w111 * p111[2];
}

// bilinear warp of a 1-channel planar volume (exact round-0 expression order)
__device__ __forceinline__ float trilerp1(const float* __restrict__ vol,
                                          float cz, float cy, float cx) {
    float z0f = floorf(cz), y0f = floorf(cy), x0f = floorf(cx);
    float wz = cz - z0f, wy = cy - y0f, wx = cx - x0f;
    int z0 = (int)z0f, y0 = (int)y0f, x0 = (int)x0f;
    int z1 = min(z0 + 1, DD - 1);
    int y1 = min(y0 + 1, DD - 1);
    int x1 = min(x0 + 1, DD - 1);
    float omz = 1.0f - wz, omy = 1.0f - wy, omx = 1.0f - wx;
    int zs0 = z0 << 14, zs1 = z1 << 14;
    int ys0 = y0 << 7,  ys1 = y1 << 7;
    return omz * omy * omx * vol[zs0 + ys0 + x0]
         + omz * omy * wx  * vol[zs0 + ys0 + x1]
         + omz * wy * omx  * vol[zs0 + ys1 + x0]
         + omz * wy * wx   * vol[zs0 + ys1 + x1]
         + wz * omy * omx  * vol[zs1 + ys0 + x0]
         + wz * omy * wx   * vol[zs1 + ys0 + x1]
         + wz * wy * omx   * vol[zs1 + ys1 + x0]
         + wz * wy * wx    * vol[zs1 + ys1 + x1];
}

// ===========================================================================
// MAIN PATH: workspace ping-pong, 2 independent voxels per thread (ILP test)
// ===========================================================================

// ---------------------------------------------------------------------------
// init: 4 voxels/thread, every access dwordx4.
// planar dvf -> interleaved A (scaled 2^-7) + dvf pass-through copy.
// grid = NV/1024 = 2048 blocks
// ---------------------------------------------------------------------------
__global__ __launch_bounds__(256)
void init_fused_kernel(const float* __restrict__ dvf,
                       float* __restrict__ A,
                       float* __restrict__ dvf_out) {
    int vbid = swz(blockIdx.x, 2048 / NXCD);
    int base = vbid * 1024 + threadIdx.x * 4;   // 4 consecutive voxels

    float4 a = *(const float4*)(dvf + base);
    float4 b = *(const float4*)(dvf + base + NV);
    float4 c = *(const float4*)(dvf + base + 2 * NV);

    *(float4*)(dvf_out + base)          = a;
    *(float4*)(dvf_out + base + NV)     = b;
    *(float4*)(dvf_out + base + 2 * NV) = c;

    float4 o0 = make_float4(a.x * INV_SCALE, b.x * INV_SCALE, c.x * INV_SCALE,
                            a.y * INV_SCALE);
    float4 o1 = make_float4(b.y * INV_SCALE, c.y * INV_SCALE, a.z * INV_SCALE,
                            b.z * INV_SCALE);
    float4 o2 = make_float4(c.z * INV_SCALE, a.w * INV_SCALE, b.w * INV_SCALE,
                            c.w * INV_SCALE);
    float* p = A + 3 * base;
    *(float4*)(p)     = o0;
    *(float4*)(p + 4) = o1;
    *(float4*)(p + 8) = o2;
}

// ---------------------------------------------------------------------------
// squaring step (steps 1..6), 2 voxels/thread from independent z-halves:
// voxel tid (z<64) and tid+NV/2 (z>=64).  Two fully independent gather
// chains per thread -> 2x memory-level parallelism at identical request
// count and identical per-voxel arithmetic (bit-identical results).
// grid = NV/512 = 4096 blocks
// ---------------------------------------------------------------------------
__global__ __launch_bounds__(256)
void step_kernel(const float* __restrict__ src, float* __restrict__ dst) {
    int vbid = swz(blockIdx.x, 4096 / NXCD);
    int tidA = vbid * 256 + threadIdx.x;   // z in [0,64)
    int tidB = tidA + NV / 2;              // z in [64,128)

    int zA, yA, xA, zB, yB, xB;
    unpack_zyx(tidA, zA, yA, xA);
    unpack_zyx(tidB, zB, yB, xB);

    // both own-loads issue independently
    const float* sA = src + 3 * tidA;
    const float* sB = src + 3 * tidB;
    float a0 = sA[0], a1 = sA[1], a2 = sA[2];
    float b0 = sB[0], b1 = sB[1], b2 = sB[2];

    float czA = clampd((float)zA + a0);
    float cyA = clampd((float)yA + a1);
    float cxA = clampd((float)xA + a2);
    float czB = clampd((float)zB + b0);
    float cyB = clampd((float)yB + b1);
    float cxB = clampd((float)xB + b2);

    float rA0, rA1, rA2, rB0, rB1, rB2;
    trilerp3(src, czA, cyA, cxA, rA0, rA1, rA2);
    trilerp3(src, czB, cyB, cxB, rB0, rB1, rB2);

    rA0 += a0; rA1 += a1; rA2 += a2;
    rB0 += b0; rB1 += b1; rB2 += b2;

    float* pA = dst + 3 * tidA;
    float* pB = dst + 3 * tidB;
    pA[0] = rA0; pA[1] = rA1; pA[2] = rA2;
    pB[0] = rB0; pB[1] = rB1; pB[2] = rB2;
}

// ---------------------------------------------------------------------------
// fused step 7 + final, 2 voxels/thread (same pairing).  Computes ddf in
// registers, writes planar ddf, then warps moving_image (bilinear) and
// moving_label (nearest) with the register ddf.
// grid = NV/512 = 4096 blocks
// ---------------------------------------------------------------------------
__global__ __launch_bounds__(256)
void step7_final_kernel(const float* __restrict__ src,
                        const float* __restrict__ mimg,
                        const float* __restrict__ mlab,
                        float* __restrict__ ddf_out,
                        float* __restrict__ pred_img,
                        float* __restrict__ pred_lab) {
    int vbid = swz(blockIdx.x, 4096 / NXCD);
    int tidA = vbid * 256 + threadIdx.x;
    int tidB = tidA + NV / 2;

    int zA, yA, xA, zB, yB, xB;
    unpack_zyx(tidA, zA, yA, xA);
    unpack_zyx(tidB, zB, yB, xB);

    const float* sA = src + 3 * tidA;
    const float* sB = src + 3 * tidB;
    float a0 = sA[0], a1 = sA[1], a2 = sA[2];
    float b0 = sB[0], b1 = sB[1], b2 = sB[2];

    float czA = clampd((float)zA + a0);
    float cyA = clampd((float)yA + a1);
    float cxA = clampd((float)xA + a2);
    float czB = clampd((float)zB + b0);
    float cyB = clampd((float)yB + b1);
    float cxB = clampd((float)xB + b2);

    float rA0, rA1, rA2, rB0, rB1, rB2;
    trilerp3(src, czA, cyA, cxA, rA0, rA1, rA2);
    trilerp3(src, czB, cyB, cxB, rB0, rB1, rB2);

    rA0 += a0; rA1 += a1; rA2 += a2;
    rB0 += b0; rB1 += b1; rB2 += b2;

    ddf_out[tidA]          = rA0;
    ddf_out[tidA + NV]     = rA1;
    ddf_out[tidA + 2 * NV] = rA2;
    ddf_out[tidB]          = rB0;
    ddf_out[tidB + NV]     = rB1;
    ddf_out[tidB + 2 * NV] = rB2;

    float fzA = clampd((float)zA + rA0);
    float fyA = clampd((float)yA + rA1);
    float fxA = clampd((float)xA + rA2);
    float fzB = clampd((float)zB + rB0);
    float fyB = clampd((float)yB + rB1);
    float fxB = clampd((float)xB + rB2);

    pred_img[tidA] = trilerp1(mimg, fzA, fyA, fxA);
    pred_img[tidB] = trilerp1(mimg, fzB, fyB, fxB);

    {
        int zi = (int)rintf(fzA), yi = (int)rintf(fyA), xi = (int)rintf(fxA);
        pred_lab[tidA] = mlab[(zi << 14) + (yi << 7) + xi];
    }
    {
        int zi = (int)rintf(fzB), yi = (int)rintf(fyB), xi = (int)rintf(fxB);
        pred_lab[tidB] = mlab[(zi << 14) + (yi << 7) + xi];
    }
}

// ===========================================================================
// FALLBACK PATH (workspace too small): round-0 verified 261 µs pipeline
// ===========================================================================

__global__ __launch_bounds__(256)
void init_kernel_fb(const float* __restrict__ dvf, float* __restrict__ A) {
    int tid = blockIdx.x * blockDim.x + threadIdx.x;
    float d0 = dvf[tid] * INV_SCALE;
    float d1 = dvf[tid + NV] * INV_SCALE;
    float d2 = dvf[tid + 2 * NV] * INV_SCALE;
    float* p = A + 3 * tid;
    p[0] = d0; p[1] = d1; p[2] = d2;
}

template <bool PLANAR_OUT>
__global__ __launch_bounds__(256)
void step_kernel_fb(const float* __restrict__ src, float* __restrict__ dst) {
    int tid = blockIdx.x * blockDim.x + threadIdx.x;
    int z, y, x;
    unpack_zyx(tid, z, y, x);
    const float* s = src + 3 * tid;
    float d0 = s[0], d1 = s[1], d2 = s[2];
    float cz = clampd((float)z + d0);
    float cy = clampd((float)y + d1);
    float cx = clampd((float)x + d2);
    float r0, r1, r2;
    trilerp3(src, cz, cy, cx, r0, r1, r2);
    r0 += d0; r1 += d1; r2 += d2;
    if (PLANAR_OUT) {
        dst[tid]          = r0;
        dst[tid + NV]     = r1;
        dst[tid + 2 * NV] = r2;
    } else {
        float* p = dst + 3 * tid;
        p[0] = r0; p[1] = r1; p[2] = r2;
    }
}

__global__ __launch_bounds__(256)
void final_kernel_fb(const float* __restrict__ ddf,
                     const float* __restrict__ mimg,
                     const float* __restrict__ mlab,
                     const float* __restrict__ dvf,
                     float* __restrict__ pred_img,
                     float* __restrict__ pred_lab,
                     float* __restrict__ dvf_out) {
    int tid = blockIdx.x * blockDim.x + threadIdx.x;
    int z, y, x;
    unpack_zyx(tid, z, y, x);
    float d0 = ddf[tid];
    float d1 = ddf[tid + NV];
    float d2 = ddf[tid + 2 * NV];
    float cz = clampd((float)z + d0);
    float cy = clampd((float)y + d1);
    float cx = clampd((float)x + d2);
    pred_img[tid] = trilerp1(mimg, cz, cy, cx);
    int zi = (int)rintf(cz);
    int yi = (int)rintf(cy);
    int xi = (int)rintf(cx);
    pred_lab[tid] = mlab[(zi << 14) + (yi << 7) + xi];
    dvf_out[tid]          = dvf[tid];
    dvf_out[tid + NV]     = dvf[tid + NV];
    dvf_out[tid + 2 * NV] = dvf[tid + 2 * NV];
}

// ===========================================================================

extern "C" void kernel_launch(void* const* d_in, const int* in_sizes, int n_in,
                              void* d_out, int out_size, void* d_ws, size_t ws_size,
                              hipStream_t stream) {
    const float* dvf  = (const float*)d_in[0];
    const float* mimg = (const float*)d_in[1];
    // d_in[2] = fixed_image: unused by the reference outputs
    const float* mlab = (const float*)d_in[3];

    float* out      = (float*)d_out;
    float* ddf_out  = out;              // slot 0: ddf  [3,D,H,W]
    float* pred_img = out + 3 * NV;     // slot 1
    float* pred_lab = out + 4 * NV;     // slot 2
    float* dvf_out  = out + 5 * NV;     // slot 3: dvf pass-through

    dim3 block(256);
    dim3 grid(NV / 256);       // 8192 blocks (fallback kernels)
    dim3 hgrid(NV / 512);      // 4096 blocks (2-voxel step kernels)
    dim3 igrid(NV / 1024);     // 2048 blocks (vectorized init)

    size_t need = (size_t)2 * NV * 3 * sizeof(float);  // 48 MiB ping-pong
    if (d_ws != nullptr && ws_size >= need) {
        float* A = (float*)d_ws;          // interleaved 12B
        float* B = A + (size_t)3 * NV;
        init_fused_kernel<<<igrid, block, 0, stream>>>(dvf, A, dvf_out);
        step_kernel<<<hgrid, block, 0, stream>>>(A, B);  // 1
        step_kernel<<<hgrid, block, 0, stream>>>(B, A);  // 2
        step_kernel<<<hgrid, block, 0, stream>>>(A, B);  // 3
        step_kernel<<<hgrid, block, 0, stream>>>(B, A);  // 4
        step_kernel<<<hgrid, block, 0, stream>>>(A, B);  // 5
        step_kernel<<<hgrid, block, 0, stream>>>(B, A);  // 6
        step7_final_kernel<<<hgrid, block, 0, stream>>>(A, mimg, mlab,
                                                        ddf_out, pred_img,
                                                        pred_lab);        // 7
    } else {
        // fallback: round-0 verified pipeline (scratch inside d_out)
        float* A = dvf_out;
        float* B = ddf_out;
        init_kernel_fb<<<grid, block, 0, stream>>>(dvf, A);
        step_kernel_fb<false><<<grid, block, 0, stream>>>(A, B);  // 1
        step_kernel_fb<false><<<grid, block, 0, stream>>>(B, A);  // 2
        step_kernel_fb<false><<<grid, block, 0, stream>>>(A, B);  // 3
        step_kernel_fb<false><<<grid, block, 0, stream>>>(B, A);  // 4
        step_kernel_fb<false><<<grid, block, 0, stream>>>(A, B);  // 5
        step_kernel_fb<false><<<grid, block, 0, stream>>>(B, A);  // 6
        step_kernel_fb<true ><<<grid, block, 0, stream>>>(A, B);  // 7
        final_kernel_fb<<<grid, block, 0, stream>>>(B, mimg, mlab, dvf,
                                                    pred_img, pred_lab, dvf_out);
    }
}